// Round 12
// baseline (78.224 us; speedup 1.0000x reference)
//
#include <hip/hip_runtime.h>
#include <stdint.h>

#define NHEADS 16
#define HDIM 64
#define WIN 33
#define BATCH 2
#define SEQ 2048
#define MROWS (BATCH*SEQ)   // 4096
#define PARTSZ (BATCH*NHEADS*SEQ*HDIM)  // 4194304

using f32x4 = __attribute__((ext_vector_type(4))) float;
using bf16x8 = __attribute__((ext_vector_type(8))) short;

__device__ inline short f2bf(float f) {
    union { float f; uint32_t u; } c; c.f = f;
    uint32_t u = c.u;
    uint32_t r = (u + 0x7fffu + ((u >> 16) & 1u)) >> 16;
    return (short)(uint16_t)r;
}

#define GLL16(g, l) __builtin_amdgcn_global_load_lds( \
        (const __attribute__((address_space(1))) void*)(g), \
        (__attribute__((address_space(3))) void*)(l), 16, 0, 0)
#define WAITV(n)  asm volatile("s_waitcnt vmcnt(" #n ")" ::: "memory")
#define WAITL0()  asm volatile("s_waitcnt lgkmcnt(0)" ::: "memory")
#define SBAR()    __builtin_amdgcn_s_barrier()
#define SCHED0()  __builtin_amdgcn_sched_barrier(0)

// ---------------- fused f32->bf16 for x, w_qkv, w_out ----------------
__global__ __launch_bounds__(256)
void cvt3_k(const float* __restrict__ x,  short* __restrict__ xb,
            const float* __restrict__ w1, short* __restrict__ w1b,
            const float* __restrict__ w2, short* __restrict__ w2b)
{
    const int i = blockIdx.x * 256 + threadIdx.x;
    const float* src; short* dstp; int off;
    if (i < 524288)      { src = x;  dstp = xb;  off = i; }
    else if (i < 917504) { src = w1; dstp = w1b; off = i - 524288; }
    else                 { src = w2; dstp = w2b; off = i - 917504; }
    const f32x4 v0 = *(const f32x4*)(src + (size_t)off * 8);
    const f32x4 v1 = *(const f32x4*)(src + (size_t)off * 8 + 4);
    bf16x8 o;
    o[0] = f2bf(v0[0]); o[1] = f2bf(v0[1]); o[2] = f2bf(v0[2]); o[3] = f2bf(v0[3]);
    o[4] = f2bf(v1[0]); o[5] = f2bf(v1[1]); o[6] = f2bf(v1[2]); o[7] = f2bf(v1[3]);
    *(bf16x8*)(dstp + (size_t)off * 8) = o;
}

// ================= GEMM1: qkv projection, 128x192, single-barrier K-tile ====
// C[4096,3072] = A[4096,1024] * B[3072,1024]^T + bias -> bf16 scatter.
// Geometry unchanged from r11 (proven): tile 128x192, grid 512 = 2 blocks/CU,
// LDS 80 KB (2dbuf), 8 waves 2M x 4N, BK=64, slot swizzle (0 conflicts).
// Schedule change (r12): ONE barrier per K-tile, and ds_reads are NOT drained
// before MFMA -- the compiler interleaves MFMA with arriving reads via its own
// fine-grained lgkmcnt (G7). Per kt:
//   {14 ds_read + 24 MFMA, compiler-scheduled, setprio-wrapped}
//   WAITL0  (all my reads of buf[par] retired -> buf may be overwritten)
//   WAITV(0) (kt+1's 5 GLLs -- issued one full kt (~2700cy) ago -- landed; free)
//   SBAR    (publishes: buf[par] free block-wide AND kt+1's LDS contents)
//   STAGE_AB(kt+2) -> buf[par]  (strictly post-barrier => no WAR race)
// kt+2's stage retires at kt+1's WAITV(0), published by kt+1's SBAR, read at
// kt+2. Edges: kt=13 stages kt15; kt=14 barrier only; kt=15 no tail sync.
__global__ __launch_bounds__(512, 4)
void gemm1_k(const short* __restrict__ A, const short* __restrict__ Bm,
             const float* __restrict__ bias, short* __restrict__ dst)
{
    __shared__ short As[2][8192];    // 2 dbuf x [128][64] bf16 = 32 KB
    __shared__ short Bs[2][12288];   // 2 dbuf x [192][64] bf16 = 48 KB
    const int tid  = threadIdx.x;
    const int lane = tid & 63;
    const int wv   = tid >> 6;
    const int wr = wv >> 2, wc = wv & 3;     // 2M x 4N waves
    const int q15 = lane & 15, p = lane >> 4;

    int bid = blockIdx.x;                    // 512 blocks = 8 XCD chunks of 64
    bid = (bid & 7) * 64 + (bid >> 3);       // bijective chunked swizzle
    const int tmi = bid & 31, tni = bid >> 5;
    const int tm = tmi << 7;                 // m-tile base (128)
    const int tn = tni * 192;                // n-tile base = head tni

    // staging: one GLL16 = 512 lanes x 16B = 64 rows x 128B; global source
    // slot pre-swizzled ssl = (t&7) ^ ((t>>4)&7) so LDS dest stays linear.
    const int ssl = (tid & 7) ^ ((tid >> 4) & 7);
    const short* Ag = A  + (size_t)(tm + (tid >> 3)) * 1024 + ssl * 8;
    const short* Bg = Bm + (size_t)(tn + (tid >> 3)) * 1024 + ssl * 8;

#define STGA(d, rowoff, koff) GLL16(Ag + (size_t)(rowoff) * 1024 + (koff), &As[d][(rowoff) * 64 + tid * 8])
#define STGB(d, rowoff, koff) GLL16(Bg + (size_t)(rowoff) * 1024 + (koff), &Bs[d][(rowoff) * 64 + tid * 8])
#define STAGE_AB(d, koff) do { STGA(d,0,koff); STGA(d,64,koff); \
                               STGB(d,0,koff); STGB(d,64,koff); STGB(d,128,koff); } while (0)

    f32x4 acc[4][3];
#pragma unroll
    for (int mi = 0; mi < 4; ++mi)
#pragma unroll
        for (int ni = 0; ni < 3; ++ni) acc[mi][ni] = (f32x4)0.f;

    // fragment reads: A row = wr*64 + mi*16 + q15; B row = wc*48 + ni*16 + q15.
    // (row>>1)&7 == q15>>1 for all frags (64wr, 48wc, 16ni are 0 mod 16).
    const int swz  = q15 >> 1;
    const int arow = (wr * 64 + q15) * 64;
    const int brow = (wc * 48 + q15) * 64;
    const int s0o  = (p ^ swz) * 8;          // ks=0 slot (shorts)
    const int s1o  = ((4 + p) ^ swz) * 8;    // ks=1

    // prologue: kt0 -> d0 (5 loads), kt1 -> d1 (5 loads)
    STAGE_AB(0, 0);
    STAGE_AB(1, 64);
    WAITV(5); SBAR(); SCHED0();              // kt0 landed; kt1's 5 in flight

#pragma unroll
    for (int kt = 0; kt < 16; ++kt) {
        const int par = kt & 1;
        const short* asd = &As[par][0];
        const short* bsd = &Bs[par][0];
        bf16x8 af[4][2], bf[3][2];

        // reads + MFMA, compiler-interleaved (no forced lgkm drain first)
#pragma unroll
        for (int mi = 0; mi < 4; ++mi) {
            af[mi][0] = *(const bf16x8*)(asd + arow + mi * 1024 + s0o);
            af[mi][1] = *(const bf16x8*)(asd + arow + mi * 1024 + s1o);
        }
#pragma unroll
        for (int ni = 0; ni < 3; ++ni) {
            bf[ni][0] = *(const bf16x8*)(bsd + brow + ni * 1024 + s0o);
            bf[ni][1] = *(const bf16x8*)(bsd + brow + ni * 1024 + s1o);
        }
        __builtin_amdgcn_s_setprio(1);
#pragma unroll
        for (int mi = 0; mi < 4; ++mi)
#pragma unroll
            for (int ni = 0; ni < 3; ++ni) {
                acc[mi][ni] = __builtin_amdgcn_mfma_f32_16x16x32_bf16(af[mi][0], bf[ni][0], acc[mi][ni], 0, 0, 0);
                acc[mi][ni] = __builtin_amdgcn_mfma_f32_16x16x32_bf16(af[mi][1], bf[ni][1], acc[mi][ni], 0, 0, 0);
            }
        __builtin_amdgcn_s_setprio(0);

        if (kt < 15) {
            WAITL0(); WAITV(0); SBAR(); SCHED0();
            if (kt < 14) STAGE_AB(par, (kt + 2) * 64);
        }
    }
#undef STGA
#undef STGB
#undef STAGE_AB

    // epilogue: head h = tni; scatter q/k [bh][s][d], v^T [bh][d][s]
#pragma unroll
    for (int mi = 0; mi < 4; ++mi) {
#pragma unroll
        for (int ni = 0; ni < 3; ++ni) {
            const int c    = wc * 48 + ni * 16 + q15;   // 0..191 within head
            const int part = c >> 6;
            const int dd   = c & 63;
            const int row0 = tm + wr * 64 + mi * 16 + p * 4;
            const float bv = bias[tn + c];
            const size_t pbase = (size_t)part * PARTSZ;
#pragma unroll
            for (int r = 0; r < 4; ++r) {
                const int row = row0 + r;               // b*2048 + s
                const int b   = row >> 11;
                const int s   = row & 2047;
                const size_t hb = pbase + ((((size_t)b << 4) + tni) << 17);
                const size_t addr = (part == 2)
                    ? hb + ((size_t)dd << 11) + s
                    : hb + ((size_t)s << 6) + dd;
                dst[addr] = f2bf(acc[mi][ni][r] + bv);
            }
        }
    }
}

// ================= GEMM2: output projection (r6-verified) =================
__global__ __launch_bounds__(256, 3)
void gemm2_k(const short* __restrict__ A, const short* __restrict__ Bm,
             const float* __restrict__ bias, float* __restrict__ C)
{
    __shared__ short As[3][2048];   // 3 x 64x32 = 12 KB
    __shared__ short Bs[3][4096];   // 3 x 128x32 = 24 KB
    const int tid  = threadIdx.x;
    const int lane = tid & 63;
    const int wc   = tid >> 6;
    const int q15 = lane & 15, p = lane >> 4;

    int bid = blockIdx.x;                 // 512 blocks
    bid = (bid & 7) * 64 + (bid >> 3);
    const int tm = (bid & 63) << 6;
    const int tn = (bid >> 6) << 7;

    const int rb  = tid >> 2;
    const int ssl = (tid & 3) ^ ((rb >> 1) & 3);
    const short* Ag = A  + (size_t)(tm + rb) * 1024 + ssl * 8;
    const short* Bg = Bm + (size_t)(tn + rb) * 1024 + ssl * 8;

#define STAGE2(tt, db) do {                                  \
        const int _ko = (tt) * 32;                           \
        GLL16(Ag + _ko,         &As[db][tid * 8]);           \
        GLL16(Bg + _ko,         &Bs[db][tid * 8]);           \
        GLL16(Bg + _ko + 65536, &Bs[db][2048 + tid * 8]);    \
    } while (0)

    f32x4 acc[4][2];
#pragma unroll
    for (int mi = 0; mi < 4; ++mi)
#pragma unroll
        for (int ni = 0; ni < 2; ++ni) acc[mi][ni] = (f32x4)0.f;

    int oA[4], oB[2];
#pragma unroll
    for (int mi = 0; mi < 4; ++mi) {
        const int row = mi * 16 + q15;
        oA[mi] = row * 32 + (p ^ ((row >> 1) & 3)) * 8;
    }
#pragma unroll
    for (int ni = 0; ni < 2; ++ni) {
        const int row = wc * 32 + ni * 16 + q15;
        oB[ni] = row * 32 + (p ^ ((row >> 1) & 3)) * 8;
    }

    STAGE2(0, 0); STAGE2(1, 1);
    WAITV(3); SBAR(); SCHED0();

    for (int t = 0; t < 32; ++t) {
        const int cb = t % 3;
        if (t < 30) STAGE2(t + 2, (t + 2) % 3);
        bf16x8 af[4], bfr[2];
#pragma unroll
        for (int mi = 0; mi < 4; ++mi) af[mi] = *(const bf16x8*)(&As[cb][oA[mi]]);
#pragma unroll
        for (int ni = 0; ni < 2; ++ni) bfr[ni] = *(const bf16x8*)(&Bs[cb][oB[ni]]);
        __builtin_amdgcn_s_setprio(1);
#pragma unroll
        for (int mi = 0; mi < 4; ++mi)
#pragma unroll
            for (int ni = 0; ni < 2; ++ni)
                acc[mi][ni] = __builtin_amdgcn_mfma_f32_16x16x32_bf16(af[mi], bfr[ni], acc[mi][ni], 0, 0, 0);
        __builtin_amdgcn_s_setprio(0);
        SCHED0();
        if (t < 30)       { WAITV(3); SBAR(); SCHED0(); }
        else if (t == 30) { WAITV(0); SBAR(); SCHED0(); }
    }
#undef STAGE2

#pragma unroll
    for (int mi = 0; mi < 4; ++mi) {
#pragma unroll
        for (int ni = 0; ni < 2; ++ni) {
            const int col  = tn + wc * 32 + ni * 16 + q15;
            const int row0 = tm + mi * 16 + p * 4;
            const float bv = bias[col];
#pragma unroll
            for (int r = 0; r < 4; ++r)
                C[(size_t)(row0 + r) * 1024 + col] = acc[mi][ni][r] + bv;
        }
    }
}

// ---------------- sliding-window attention via MFMA (r4-verified) ----------------
__global__ __launch_bounds__(256)
void swattn4_k(const short* __restrict__ qkvb, short* __restrict__ ctx)
{
    __shared__ short Ks[96 * 64];
    __shared__ short Vt[64 * 104];
    const int tid  = threadIdx.x;
    const int lane = tid & 63;
    const int w    = tid >> 6;
    const int q15  = lane & 15;
    const int p    = lane >> 4;
    const int tile = blockIdx.x & 31;
    const int bh   = blockIdx.x >> 5;
    const int b    = bh >> 4, h = bh & 15;
    const int s0   = tile * 64;
    const short* qbase  = qkvb + ((size_t)bh << 17);
    const short* kbase  = qbase + PARTSZ;
    const short* vtbase = qbase + 2 * PARTSZ;

#pragma unroll
    for (int c = 0; c < 3; ++c) {
        const int idx = c * 256 + tid;
        const int row = idx >> 3;
        const int sli = idx & 7;
        const int pos = s0 - 16 + row;
        bf16x8 kv = (bf16x8)0;
        if (pos >= 0 && pos < SEQ)
            kv = *(const bf16x8*)(kbase + (size_t)pos * 64 + sli * 8);
        *(bf16x8*)(Ks + row * 64 + ((sli ^ (row & 7)) << 3)) = kv;
    }
#pragma unroll
    for (int c = 0; c < 4; ++c) {
        const int idx = c * 256 + tid;
        const int d   = idx >> 4;
        const int sli = idx & 15;
        if (sli < 12) {
            const int pos = s0 - 16 + sli * 8;
            bf16x8 vv = (bf16x8)0;
            if (pos >= 0 && pos <= SEQ - 8)
                vv = *(const bf16x8*)(vtbase + (size_t)d * SEQ + pos);
            *(bf16x8*)(Vt + d * 104 + sli * 8) = vv;
        }
    }
    __syncthreads();

    const int qrow = s0 + w * 16 + q15;
    const bf16x8 qf0 = *(const bf16x8*)(qbase + (size_t)qrow * 64 + p * 8);
    const bf16x8 qf1 = *(const bf16x8*)(qbase + (size_t)qrow * 64 + 32 + p * 8);

    f32x4 accs[6];
#pragma unroll
    for (int t = 0; t < 6; ++t) accs[t] = (f32x4)0.f;
#pragma unroll
    for (int t = 0; t < 6; ++t) {
        const int row = t * 16 + q15;
        const int sw  = row & 7;
        const bf16x8 kf0 = *(const bf16x8*)(Ks + row * 64 + ((p ^ sw) << 3));
        const bf16x8 kf1 = *(const bf16x8*)(Ks + row * 64 + (((p + 4) ^ sw) << 3));
        accs[t] = __builtin_amdgcn_mfma_f32_16x16x32_bf16(kf0, qf0, accs[t], 0, 0, 0);
        accs[t] = __builtin_amdgcn_mfma_f32_16x16x32_bf16(kf1, qf1, accs[t], 0, 0, 0);
    }

    const int qloc = w * 16 + q15;
    float m = -1e30f;
#pragma unroll
    for (int t = 0; t < 6; ++t)
#pragma unroll
        for (int r = 0; r < 4; ++r) {
            const int n = t * 16 + p * 4 + r;
            const bool valid = (n >= qloc) && (n <= qloc + 32);
            const float v = valid ? accs[t][r] * 0.125f : -1e30f;
            accs[t][r] = v;
            m = fmaxf(m, v);
        }
    m = fmaxf(m, __shfl_xor(m, 16));
    m = fmaxf(m, __shfl_xor(m, 32));
    float sum = 0.f;
#pragma unroll
    for (int t = 0; t < 6; ++t)
#pragma unroll
        for (int r = 0; r < 4; ++r) {
            const float e = __expf(accs[t][r] - m);
            accs[t][r] = e;
            sum += e;
        }
    sum += __shfl_xor(sum, 16);
    sum += __shfl_xor(sum, 32);
    const float inv = 1.f / sum;

    uint32_t pk[6][2];
#pragma unroll
    for (int t = 0; t < 6; ++t)
#pragma unroll
        for (int rp = 0; rp < 2; ++rp) {
            const float lo = accs[t][2 * rp] * inv;
            const float hi = accs[t][2 * rp + 1] * inv;
            uint32_t o;
            asm("v_cvt_pk_bf16_f32 %0, %1, %2" : "=v"(o) : "v"(lo), "v"(hi));
            pk[t][rp] = o;
        }
    uint32_t afu[3][4];
#pragma unroll
    for (int t = 0; t < 6; ++t)
#pragma unroll
        for (int rp = 0; rp < 2; ++rp)
#pragma unroll
            for (int bb = 0; bb < 2; ++bb) {
                const int src = q15 + (((2 * p + bb) & 3) << 4);
                const uint32_t v = __shfl((int)pk[t][rp], src);
                if ((t & 1) == (p >> 1))
                    afu[t >> 1][2 * bb + rp] = v;
            }
    union U { uint32_t u[4]; bf16x8 v; };
    U u0, u1, u2;
#pragma unroll
    for (int f = 0; f < 4; ++f) { u0.u[f] = afu[0][f]; u1.u[f] = afu[1][f]; u2.u[f] = afu[2][f]; }
    const bf16x8 af0 = u0.v, af1 = u1.v, af2 = u2.v;

    f32x4 accp[4];
#pragma unroll
    for (int dt = 0; dt < 4; ++dt) accp[dt] = (f32x4)0.f;
#pragma unroll
    for (int dt = 0; dt < 4; ++dt) {
        const short* vr = Vt + (dt * 16 + q15) * 104 + p * 8;
        const bf16x8 vf0 = *(const bf16x8*)(vr);
        const bf16x8 vf1 = *(const bf16x8*)(vr + 32);
        const bf16x8 vf2 = *(const bf16x8*)(vr + 64);
        accp[dt] = __builtin_amdgcn_mfma_f32_16x16x32_bf16(af0, vf0, accp[dt], 0, 0, 0);
        accp[dt] = __builtin_amdgcn_mfma_f32_16x16x32_bf16(af1, vf1, accp[dt], 0, 0, 0);
        accp[dt] = __builtin_amdgcn_mfma_f32_16x16x32_bf16(af2, vf2, accp[dt], 0, 0, 0);
    }

#pragma unroll
    for (int dt = 0; dt < 4; ++dt) {
        const int d = dt * 16 + q15;
#pragma unroll
        for (int r = 0; r < 4; ++r) {
            const int s = s0 + w * 16 + p * 4 + r;
            ctx[(((size_t)(b * SEQ + s)) << 10) + h * 64 + d] = f2bf(accp[dt][r]);
        }
    }
}

// ---------------- launch ----------------
extern "C" void kernel_launch(void* const* d_in, const int* in_sizes, int n_in,
                              void* d_out, int out_size, void* d_ws, size_t ws_size,
                              hipStream_t stream)
{
    const float* x     = (const float*)d_in[0];
    const float* w_qkv = (const float*)d_in[1];
    const float* b_qkv = (const float*)d_in[2];
    const float* w_out = (const float*)d_in[3];
    const float* b_out = (const float*)d_in[4];
    float* out = (float*)d_out;

    char* ws = (char*)d_ws;
    short* x_bf    = (short*)(ws);                       // 8 MB
    short* wqkv_bf = (short*)(ws + (8ull  << 20));       // 6 MB
    short* wout_bf = (short*)(ws + (14ull << 20));       // 2 MB
    short* qkvb    = (short*)(ws + (16ull << 20));       // 24 MB: q,k [bh][s][d]; v^T [bh][d][s]
    short* ctx     = (short*)(ws + (48ull << 20));       // 8 MB

    cvt3_k<<<dim3(4096), 256, 0, stream>>>(x, x_bf, w_qkv, wqkv_bf, w_out, wout_bf);

    gemm1_k<<<dim3(512), 512, 0, stream>>>(x_bf, wqkv_bf, b_qkv, qkvb);

    swattn4_k<<<dim3((SEQ / 64) * BATCH * NHEADS), 256, 0, stream>>>(qkvb, (short*)ctx);

    gemm2_k<<<dim3(512), 256, 0, stream>>>(ctx, wout_bf, b_out, out);
}

// Round 13
// 70.571 us; speedup vs baseline: 1.1084x; 1.1084x over previous
//
#include <hip/hip_runtime.h>
#include <stdint.h>

#define NHEADS 16
#define HDIM 64
#define WIN 33
#define BATCH 2
#define SEQ 2048
#define MROWS (BATCH*SEQ)   // 4096
#define PARTSZ (BATCH*NHEADS*SEQ*HDIM)  // 4194304

using f32x4 = __attribute__((ext_vector_type(4))) float;
using bf16x8 = __attribute__((ext_vector_type(8))) short;

__device__ inline short f2bf(float f) {
    union { float f; uint32_t u; } c; c.f = f;
    uint32_t u = c.u;
    uint32_t r = (u + 0x7fffu + ((u >> 16) & 1u)) >> 16;
    return (short)(uint16_t)r;
}

#define GLL16(g, l) __builtin_amdgcn_global_load_lds( \
        (const __attribute__((address_space(1))) void*)(g), \
        (__attribute__((address_space(3))) void*)(l), 16, 0, 0)
#define WAITV(n)  asm volatile("s_waitcnt vmcnt(" #n ")" ::: "memory")
#define WAITL0()  asm volatile("s_waitcnt lgkmcnt(0)" ::: "memory")
#define SBAR()    __builtin_amdgcn_s_barrier()
#define SCHED0()  __builtin_amdgcn_sched_barrier(0)

// ---------------- fused f32->bf16 for x, w_qkv, w_out ----------------
__global__ __launch_bounds__(256)
void cvt3_k(const float* __restrict__ x,  short* __restrict__ xb,
            const float* __restrict__ w1, short* __restrict__ w1b,
            const float* __restrict__ w2, short* __restrict__ w2b)
{
    const int i = blockIdx.x * 256 + threadIdx.x;
    const float* src; short* dstp; int off;
    if (i < 524288)      { src = x;  dstp = xb;  off = i; }
    else if (i < 917504) { src = w1; dstp = w1b; off = i - 524288; }
    else                 { src = w2; dstp = w2b; off = i - 917504; }
    const f32x4 v0 = *(const f32x4*)(src + (size_t)off * 8);
    const f32x4 v1 = *(const f32x4*)(src + (size_t)off * 8 + 4);
    bf16x8 o;
    o[0] = f2bf(v0[0]); o[1] = f2bf(v0[1]); o[2] = f2bf(v0[2]); o[3] = f2bf(v0[3]);
    o[4] = f2bf(v1[0]); o[5] = f2bf(v1[1]); o[6] = f2bf(v1[2]); o[7] = f2bf(v1[3]);
    *(bf16x8*)(dstp + (size_t)off * 8) = o;
}

// ================= GEMM1: qkv projection, 128x192, 2 blocks/CU (r11) =======
// C[4096,3072] = A[4096,1024] * B[3072,1024]^T + bias -> bf16 scatter.
// Tile 128x192 (BN=192 = one head), grid 512 = 2 blocks/CU, LDS 80 KB 2dbuf,
// 8 waves 2M x 4N (per-wave 64x48), BK=64. 2-phase/kt, counted WAITV(5),
// slot swizzle (HW-verified 0 conflicts). See r11 notes; best measured (77.3).
__global__ __launch_bounds__(512, 4)
void gemm1_k(const short* __restrict__ A, const short* __restrict__ Bm,
             const float* __restrict__ bias, short* __restrict__ dst)
{
    __shared__ short As[2][8192];    // 2 dbuf x [128][64] bf16 = 32 KB
    __shared__ short Bs[2][12288];   // 2 dbuf x [192][64] bf16 = 48 KB
    const int tid  = threadIdx.x;
    const int lane = tid & 63;
    const int wv   = tid >> 6;
    const int wr = wv >> 2, wc = wv & 3;     // 2M x 4N waves
    const int q15 = lane & 15, p = lane >> 4;

    int bid = blockIdx.x;                    // 512 blocks = 8 XCD chunks of 64
    bid = (bid & 7) * 64 + (bid >> 3);       // bijective chunked swizzle
    const int tmi = bid & 31, tni = bid >> 5;
    const int tm = tmi << 7;                 // m-tile base (128)
    const int tn = tni * 192;                // n-tile base = head tni

    const int ssl = (tid & 7) ^ ((tid >> 4) & 7);
    const short* Ag = A  + (size_t)(tm + (tid >> 3)) * 1024 + ssl * 8;
    const short* Bg = Bm + (size_t)(tn + (tid >> 3)) * 1024 + ssl * 8;

#define STGA(d, rowoff, koff) GLL16(Ag + (size_t)(rowoff) * 1024 + (koff), &As[d][(rowoff) * 64 + tid * 8])
#define STGB(d, rowoff, koff) GLL16(Bg + (size_t)(rowoff) * 1024 + (koff), &Bs[d][(rowoff) * 64 + tid * 8])
#define STAGE_AB(d, koff) do { STGA(d,0,koff); STGA(d,64,koff); \
                               STGB(d,0,koff); STGB(d,64,koff); STGB(d,128,koff); } while (0)

    f32x4 acc[4][3];
#pragma unroll
    for (int mi = 0; mi < 4; ++mi)
#pragma unroll
        for (int ni = 0; ni < 3; ++ni) acc[mi][ni] = (f32x4)0.f;

    const int swz  = q15 >> 1;
    const int arow = (wr * 64 + q15) * 64;
    const int brow = (wc * 48 + q15) * 64;
    const int s0o  = (p ^ swz) * 8;          // ks=0 slot (shorts)
    const int s1o  = ((4 + p) ^ swz) * 8;    // ks=1

    STAGE_AB(0, 0);
    STAGE_AB(1, 64);
    WAITV(5); SBAR(); SCHED0();              // kt0 landed; kt1's 5 in flight

#pragma unroll
    for (int kt = 0; kt < 16; ++kt) {
        const int par = kt & 1;
        const short* asd = &As[par][0];
        const short* bsd = &Bs[par][0];
        bf16x8 af[4][2], bf[3][2];

        // ---- ph1: ds_read all frags (8 A + 6 B b128); lgkm0; SBAR
#pragma unroll
        for (int mi = 0; mi < 4; ++mi) {
            af[mi][0] = *(const bf16x8*)(asd + arow + mi * 1024 + s0o);
            af[mi][1] = *(const bf16x8*)(asd + arow + mi * 1024 + s1o);
        }
#pragma unroll
        for (int ni = 0; ni < 3; ++ni) {
            bf[ni][0] = *(const bf16x8*)(bsd + brow + ni * 1024 + s0o);
            bf[ni][1] = *(const bf16x8*)(bsd + brow + ni * 1024 + s1o);
        }
        WAITL0(); SBAR(); SCHED0();          // dbuf[par] free block-wide

        // ---- ph2: stage kt+2 -> dbuf[par]; MFMA 4x3x2; gate; SBAR
        if (kt < 14) STAGE_AB(par, (kt + 2) * 64);
        __builtin_amdgcn_s_setprio(1);
#pragma unroll
        for (int mi = 0; mi < 4; ++mi)
#pragma unroll
            for (int ni = 0; ni < 3; ++ni) {
                acc[mi][ni] = __builtin_amdgcn_mfma_f32_16x16x32_bf16(af[mi][0], bf[ni][0], acc[mi][ni], 0, 0, 0);
                acc[mi][ni] = __builtin_amdgcn_mfma_f32_16x16x32_bf16(af[mi][1], bf[ni][1], acc[mi][ni], 0, 0, 0);
            }
        __builtin_amdgcn_s_setprio(0);
        SCHED0();
        if (kt < 14)       { WAITV(5); SBAR(); SCHED0(); }  // retires kt+1's 5
        else if (kt == 14) { WAITV(0); SBAR(); SCHED0(); }  // drain for kt15
    }
#undef STGA
#undef STGB
#undef STAGE_AB

    // epilogue: head h = tni; scatter q/k [bh][s][d], v^T [bh][d][s]
#pragma unroll
    for (int mi = 0; mi < 4; ++mi) {
#pragma unroll
        for (int ni = 0; ni < 3; ++ni) {
            const int c    = wc * 48 + ni * 16 + q15;   // 0..191 within head
            const int part = c >> 6;
            const int dd   = c & 63;
            const int row0 = tm + wr * 64 + mi * 16 + p * 4;
            const float bv = bias[tn + c];
            const size_t pbase = (size_t)part * PARTSZ;
#pragma unroll
            for (int r = 0; r < 4; ++r) {
                const int row = row0 + r;               // b*2048 + s
                const int b   = row >> 11;
                const int s   = row & 2047;
                const size_t hb = pbase + ((((size_t)b << 4) + tni) << 17);
                const size_t addr = (part == 2)
                    ? hb + ((size_t)dd << 11) + s
                    : hb + ((size_t)s << 6) + dd;
                dst[addr] = f2bf(acc[mi][ni][r] + bv);
            }
        }
    }
}

// ================= GEMM2: output projection, r11-style (r13 upgrade) ========
// C[4096,1024] = A[4096,1024] * B[1024,1024]^T + bias (f32 out).
// Tile 64x128, BK=64, grid 64x8 = 512 blocks = 2/CU. LDS = 2dbuf x
// (64x64 A + 128x64 B) x 2B = 48 KB. 4 waves (1M x 4N, per-wave 64x32,
// acc = 32 VGPR). Same 2-phase counted-vmcnt schedule as gemm1 (r11-proven):
//  ph1: 12 ds_read (A8+B4); WAITL0; SBAR  -> dbuf[par] free block-wide.
//  ph2: stage kt+2 (6 GLL) -> dbuf[par]; setprio + 16 MFMA; WAITV(6)
//       (queue = kt+1's 6 + kt+2's 6 -> retires exactly kt+1); SBAR.
// Edges: prologue 2 tiles, WAITV(6); kt=13 stages kt15; kt=14 WAITV(0);
// kt=15 pure compute. Staging: one GLL16 (256 thr) = 32 rows x 128B;
// thread t -> row t>>3, slot t&7, ssl = (t&7)^((t>>4)&7) (same swizzle
// family, (row>>1)&7 == (t>>4)&7; read slot = (4ks+p)^(q15>>1)).
__global__ __launch_bounds__(256, 4)
void gemm2_k(const short* __restrict__ A, const short* __restrict__ Bm,
             const float* __restrict__ bias, float* __restrict__ C)
{
    __shared__ short As[2][4096];    // 2 dbuf x [64][64] bf16 = 16 KB
    __shared__ short Bs[2][8192];    // 2 dbuf x [128][64] bf16 = 32 KB
    const int tid  = threadIdx.x;
    const int lane = tid & 63;
    const int wc   = tid >> 6;       // wave = n-quarter (1M x 4N)
    const int q15 = lane & 15, p = lane >> 4;

    int bid = blockIdx.x;                    // 512 blocks = 8 XCD chunks of 64
    bid = (bid & 7) * 64 + (bid >> 3);       // bijective chunked swizzle
    const int tm = (bid & 63) << 6;          // m-tile base (64); m fastest ->
    const int tn = (bid >> 6) << 7;          // same-XCD neighbors share B panel

    const int ssl = (tid & 7) ^ ((tid >> 4) & 7);
    const short* Ag = A  + (size_t)(tm + (tid >> 3)) * 1024 + ssl * 8;
    const short* Bg = Bm + (size_t)(tn + (tid >> 3)) * 1024 + ssl * 8;

#define STGA2(d, rowoff, koff) GLL16(Ag + (size_t)(rowoff) * 1024 + (koff), &As[d][(rowoff) * 64 + tid * 8])
#define STGB2(d, rowoff, koff) GLL16(Bg + (size_t)(rowoff) * 1024 + (koff), &Bs[d][(rowoff) * 64 + tid * 8])
#define STAGE2_AB(d, koff) do { STGA2(d,0,koff); STGA2(d,32,koff); \
                                STGB2(d,0,koff); STGB2(d,32,koff); \
                                STGB2(d,64,koff); STGB2(d,96,koff); } while (0)

    f32x4 acc[4][2];
#pragma unroll
    for (int mi = 0; mi < 4; ++mi)
#pragma unroll
        for (int ni = 0; ni < 2; ++ni) acc[mi][ni] = (f32x4)0.f;

    // frag reads: A row = mi*16 + q15; B row = wc*32 + ni*16 + q15.
    // (row>>1)&7 == q15>>1 for all frags (16mi, 32wc, 16ni are 0 mod 16).
    const int swz  = q15 >> 1;
    const int arow = q15 * 64;
    const int brow = (wc * 32 + q15) * 64;
    const int s0o  = (p ^ swz) * 8;
    const int s1o  = ((4 + p) ^ swz) * 8;

    STAGE2_AB(0, 0);
    STAGE2_AB(1, 64);
    WAITV(6); SBAR(); SCHED0();              // kt0 landed; kt1's 6 in flight

#pragma unroll
    for (int kt = 0; kt < 16; ++kt) {
        const int par = kt & 1;
        const short* asd = &As[par][0];
        const short* bsd = &Bs[par][0];
        bf16x8 af[4][2], bf[2][2];

        // ---- ph1: ds_read all frags (8 A + 4 B b128); lgkm0; SBAR
#pragma unroll
        for (int mi = 0; mi < 4; ++mi) {
            af[mi][0] = *(const bf16x8*)(asd + arow + mi * 1024 + s0o);
            af[mi][1] = *(const bf16x8*)(asd + arow + mi * 1024 + s1o);
        }
#pragma unroll
        for (int ni = 0; ni < 2; ++ni) {
            bf[ni][0] = *(const bf16x8*)(bsd + brow + ni * 1024 + s0o);
            bf[ni][1] = *(const bf16x8*)(bsd + brow + ni * 1024 + s1o);
        }
        WAITL0(); SBAR(); SCHED0();          // dbuf[par] free block-wide

        // ---- ph2: stage kt+2 -> dbuf[par]; MFMA 4x2x2; gate; SBAR
        if (kt < 14) STAGE2_AB(par, (kt + 2) * 64);
        __builtin_amdgcn_s_setprio(1);
#pragma unroll
        for (int mi = 0; mi < 4; ++mi)
#pragma unroll
            for (int ni = 0; ni < 2; ++ni) {
                acc[mi][ni] = __builtin_amdgcn_mfma_f32_16x16x32_bf16(af[mi][0], bf[ni][0], acc[mi][ni], 0, 0, 0);
                acc[mi][ni] = __builtin_amdgcn_mfma_f32_16x16x32_bf16(af[mi][1], bf[ni][1], acc[mi][ni], 0, 0, 0);
            }
        __builtin_amdgcn_s_setprio(0);
        SCHED0();
        if (kt < 14)       { WAITV(6); SBAR(); SCHED0(); }  // retires kt+1's 6
        else if (kt == 14) { WAITV(0); SBAR(); SCHED0(); }  // drain for kt15
    }
#undef STGA2
#undef STGB2
#undef STAGE2_AB

#pragma unroll
    for (int mi = 0; mi < 4; ++mi) {
#pragma unroll
        for (int ni = 0; ni < 2; ++ni) {
            const int col  = tn + wc * 32 + ni * 16 + q15;
            const int row0 = tm + mi * 16 + p * 4;
            const float bv = bias[col];
#pragma unroll
            for (int r = 0; r < 4; ++r)
                C[(size_t)(row0 + r) * 1024 + col] = acc[mi][ni][r] + bv;
        }
    }
}

// ---------------- sliding-window attention via MFMA (r4-verified) ----------------
__global__ __launch_bounds__(256)
void swattn4_k(const short* __restrict__ qkvb, short* __restrict__ ctx)
{
    __shared__ short Ks[96 * 64];
    __shared__ short Vt[64 * 104];
    const int tid  = threadIdx.x;
    const int lane = tid & 63;
    const int w    = tid >> 6;
    const int q15  = lane & 15;
    const int p    = lane >> 4;
    const int tile = blockIdx.x & 31;
    const int bh   = blockIdx.x >> 5;
    const int b    = bh >> 4, h = bh & 15;
    const int s0   = tile * 64;
    const short* qbase  = qkvb + ((size_t)bh << 17);
    const short* kbase  = qbase + PARTSZ;
    const short* vtbase = qbase + 2 * PARTSZ;

#pragma unroll
    for (int c = 0; c < 3; ++c) {
        const int idx = c * 256 + tid;
        const int row = idx >> 3;
        const int sli = idx & 7;
        const int pos = s0 - 16 + row;
        bf16x8 kv = (bf16x8)0;
        if (pos >= 0 && pos < SEQ)
            kv = *(const bf16x8*)(kbase + (size_t)pos * 64 + sli * 8);
        *(bf16x8*)(Ks + row * 64 + ((sli ^ (row & 7)) << 3)) = kv;
    }
#pragma unroll
    for (int c = 0; c < 4; ++c) {
        const int idx = c * 256 + tid;
        const int d   = idx >> 4;
        const int sli = idx & 15;
        if (sli < 12) {
            const int pos = s0 - 16 + sli * 8;
            bf16x8 vv = (bf16x8)0;
            if (pos >= 0 && pos <= SEQ - 8)
                vv = *(const bf16x8*)(vtbase + (size_t)d * SEQ + pos);
            *(bf16x8*)(Vt + d * 104 + sli * 8) = vv;
        }
    }
    __syncthreads();

    const int qrow = s0 + w * 16 + q15;
    const bf16x8 qf0 = *(const bf16x8*)(qbase + (size_t)qrow * 64 + p * 8);
    const bf16x8 qf1 = *(const bf16x8*)(qbase + (size_t)qrow * 64 + 32 + p * 8);

    f32x4 accs[6];
#pragma unroll
    for (int t = 0; t < 6; ++t) accs[t] = (f32x4)0.f;
#pragma unroll
    for (int t = 0; t < 6; ++t) {
        const int row = t * 16 + q15;
        const int sw  = row & 7;
        const bf16x8 kf0 = *(const bf16x8*)(Ks + row * 64 + ((p ^ sw) << 3));
        const bf16x8 kf1 = *(const bf16x8*)(Ks + row * 64 + (((p + 4) ^ sw) << 3));
        accs[t] = __builtin_amdgcn_mfma_f32_16x16x32_bf16(kf0, qf0, accs[t], 0, 0, 0);
        accs[t] = __builtin_amdgcn_mfma_f32_16x16x32_bf16(kf1, qf1, accs[t], 0, 0, 0);
    }

    const int qloc = w * 16 + q15;
    float m = -1e30f;
#pragma unroll
    for (int t = 0; t < 6; ++t)
#pragma unroll
        for (int r = 0; r < 4; ++r) {
            const int n = t * 16 + p * 4 + r;
            const bool valid = (n >= qloc) && (n <= qloc + 32);
            const float v = valid ? accs[t][r] * 0.125f : -1e30f;
            accs[t][r] = v;
            m = fmaxf(m, v);
        }
    m = fmaxf(m, __shfl_xor(m, 16));
    m = fmaxf(m, __shfl_xor(m, 32));
    float sum = 0.f;
#pragma unroll
    for (int t = 0; t < 6; ++t)
#pragma unroll
        for (int r = 0; r < 4; ++r) {
            const float e = __expf(accs[t][r] - m);
            accs[t][r] = e;
            sum += e;
        }
    sum += __shfl_xor(sum, 16);
    sum += __shfl_xor(sum, 32);
    const float inv = 1.f / sum;

    uint32_t pk[6][2];
#pragma unroll
    for (int t = 0; t < 6; ++t)
#pragma unroll
        for (int rp = 0; rp < 2; ++rp) {
            const float lo = accs[t][2 * rp] * inv;
            const float hi = accs[t][2 * rp + 1] * inv;
            uint32_t o;
            asm("v_cvt_pk_bf16_f32 %0, %1, %2" : "=v"(o) : "v"(lo), "v"(hi));
            pk[t][rp] = o;
        }
    uint32_t afu[3][4];
#pragma unroll
    for (int t = 0; t < 6; ++t)
#pragma unroll
        for (int rp = 0; rp < 2; ++rp)
#pragma unroll
            for (int bb = 0; bb < 2; ++bb) {
                const int src = q15 + (((2 * p + bb) & 3) << 4);
                const uint32_t v = __shfl((int)pk[t][rp], src);
                if ((t & 1) == (p >> 1))
                    afu[t >> 1][2 * bb + rp] = v;
            }
    union U { uint32_t u[4]; bf16x8 v; };
    U u0, u1, u2;
#pragma unroll
    for (int f = 0; f < 4; ++f) { u0.u[f] = afu[0][f]; u1.u[f] = afu[1][f]; u2.u[f] = afu[2][f]; }
    const bf16x8 af0 = u0.v, af1 = u1.v, af2 = u2.v;

    f32x4 accp[4];
#pragma unroll
    for (int dt = 0; dt < 4; ++dt) accp[dt] = (f32x4)0.f;
#pragma unroll
    for (int dt = 0; dt < 4; ++dt) {
        const short* vr = Vt + (dt * 16 + q15) * 104 + p * 8;
        const bf16x8 vf0 = *(const bf16x8*)(vr);
        const bf16x8 vf1 = *(const bf16x8*)(vr + 32);
        const bf16x8 vf2 = *(const bf16x8*)(vr + 64);
        accp[dt] = __builtin_amdgcn_mfma_f32_16x16x32_bf16(af0, vf0, accp[dt], 0, 0, 0);
        accp[dt] = __builtin_amdgcn_mfma_f32_16x16x32_bf16(af1, vf1, accp[dt], 0, 0, 0);
        accp[dt] = __builtin_amdgcn_mfma_f32_16x16x32_bf16(af2, vf2, accp[dt], 0, 0, 0);
    }

#pragma unroll
    for (int dt = 0; dt < 4; ++dt) {
        const int d = dt * 16 + q15;
#pragma unroll
        for (int r = 0; r < 4; ++r) {
            const int s = s0 + w * 16 + p * 4 + r;
            ctx[(((size_t)(b * SEQ + s)) << 10) + h * 64 + d] = f2bf(accp[dt][r]);
        }
    }
}

// ---------------- launch ----------------
extern "C" void kernel_launch(void* const* d_in, const int* in_sizes, int n_in,
                              void* d_out, int out_size, void* d_ws, size_t ws_size,
                              hipStream_t stream)
{
    const float* x     = (const float*)d_in[0];
    const float* w_qkv = (const float*)d_in[1];
    const float* b_qkv = (const float*)d_in[2];
    const float* w_out = (const float*)d_in[3];
    const float* b_out = (const float*)d_in[4];
    float* out = (float*)d_out;

    char* ws = (char*)d_ws;
    short* x_bf    = (short*)(ws);                       // 8 MB
    short* wqkv_bf = (short*)(ws + (8ull  << 20));       // 6 MB
    short* wout_bf = (short*)(ws + (14ull << 20));       // 2 MB
    short* qkvb    = (short*)(ws + (16ull << 20));       // 24 MB: q,k [bh][s][d]; v^T [bh][d][s]
    short* ctx     = (short*)(ws + (48ull << 20));       // 8 MB

    cvt3_k<<<dim3(4096), 256, 0, stream>>>(x, x_bf, w_qkv, wqkv_bf, w_out, wout_bf);

    gemm1_k<<<dim3(512), 512, 0, stream>>>(x_bf, wqkv_bf, b_qkv, qkvb);

    swattn4_k<<<dim3((SEQ / 64) * BATCH * NHEADS), 256, 0, stream>>>(qkvb, (short*)ctx);

    gemm2_k<<<dim3(512), 256, 0, stream>>>(ctx, wout_bf, b_out, out);
}

// Round 14
// 66.673 us; speedup vs baseline: 1.1733x; 1.0585x over previous
//
#include <hip/hip_runtime.h>
#include <stdint.h>

#define NHEADS 16
#define HDIM 64
#define WIN 33
#define BATCH 2
#define SEQ 2048
#define MROWS (BATCH*SEQ)   // 4096
#define PARTSZ (BATCH*NHEADS*SEQ*HDIM)  // 4194304

using f32x4 = __attribute__((ext_vector_type(4))) float;
using bf16x8 = __attribute__((ext_vector_type(8))) short;

__device__ inline short f2bf(float f) {
    union { float f; uint32_t u; } c; c.f = f;
    uint32_t u = c.u;
    uint32_t r = (u + 0x7fffu + ((u >> 16) & 1u)) >> 16;
    return (short)(uint16_t)r;
}

#define GLL16(g, l) __builtin_amdgcn_global_load_lds( \
        (const __attribute__((address_space(1))) void*)(g), \
        (__attribute__((address_space(3))) void*)(l), 16, 0, 0)
#define WAITV(n)  asm volatile("s_waitcnt vmcnt(" #n ")" ::: "memory")
#define WAITL0()  asm volatile("s_waitcnt lgkmcnt(0)" ::: "memory")
#define SBAR()    __builtin_amdgcn_s_barrier()
#define SCHED0()  __builtin_amdgcn_sched_barrier(0)

// ---------------- fused f32->bf16 for x, w_qkv, w_out ----------------
__global__ __launch_bounds__(256)
void cvt3_k(const float* __restrict__ x,  short* __restrict__ xb,
            const float* __restrict__ w1, short* __restrict__ w1b,
            const float* __restrict__ w2, short* __restrict__ w2b)
{
    const int i = blockIdx.x * 256 + threadIdx.x;
    const float* src; short* dstp; int off;
    if (i < 524288)      { src = x;  dstp = xb;  off = i; }
    else if (i < 917504) { src = w1; dstp = w1b; off = i - 524288; }
    else                 { src = w2; dstp = w2b; off = i - 917504; }
    const f32x4 v0 = *(const f32x4*)(src + (size_t)off * 8);
    const f32x4 v1 = *(const f32x4*)(src + (size_t)off * 8 + 4);
    bf16x8 o;
    o[0] = f2bf(v0[0]); o[1] = f2bf(v0[1]); o[2] = f2bf(v0[2]); o[3] = f2bf(v0[3]);
    o[4] = f2bf(v1[0]); o[5] = f2bf(v1[1]); o[6] = f2bf(v1[2]); o[7] = f2bf(v1[3]);
    *(bf16x8*)(dstp + (size_t)off * 8) = o;
}

// ================= GEMM1: qkv projection, 128x192, 2 blocks/CU (r11) =======
// C[4096,3072] = A[4096,1024] * B[3072,1024]^T + bias -> bf16 scatter.
// Tile 128x192 (BN=192 = one head), grid 512 = 2 blocks/CU, LDS 80 KB 2dbuf,
// 8 waves 2M x 4N (per-wave 64x48), BK=64. 2-phase/kt, counted WAITV(5),
// slot swizzle (HW-verified 0 conflicts). Best measured structure (r11/r13).
// r14: XCD 2-D locality remap -- each XCD gets an 8 tmi x 8 tni sub-grid
// (A 2MB + B 3MB ~ L2-resident) instead of m-fastest chunks (8.75MB thrash).
// Bijective: xcd = (tmi>>3) | ((tni>>3)<<2); k = (tmi&7) | ((tni&7)<<3).
__global__ __launch_bounds__(512, 4)
void gemm1_k(const short* __restrict__ A, const short* __restrict__ Bm,
             const float* __restrict__ bias, short* __restrict__ dst)
{
    __shared__ short As[2][8192];    // 2 dbuf x [128][64] bf16 = 32 KB
    __shared__ short Bs[2][12288];   // 2 dbuf x [192][64] bf16 = 48 KB
    const int tid  = threadIdx.x;
    const int lane = tid & 63;
    const int wv   = tid >> 6;
    const int wr = wv >> 2, wc = wv & 3;     // 2M x 4N waves
    const int q15 = lane & 15, p = lane >> 4;

    const int xcd = blockIdx.x & 7;          // HW XCD = blockIdx % 8
    const int kk  = blockIdx.x >> 3;         // 0..63 within-XCD index
    const int tmi = (kk & 7) | ((xcd & 3) << 3);   // 0..31
    const int tni = (kk >> 3) | ((xcd >> 2) << 3); // 0..15
    const int tm = tmi << 7;                 // m-tile base (128)
    const int tn = tni * 192;                // n-tile base = head tni

    const int ssl = (tid & 7) ^ ((tid >> 4) & 7);
    const short* Ag = A  + (size_t)(tm + (tid >> 3)) * 1024 + ssl * 8;
    const short* Bg = Bm + (size_t)(tn + (tid >> 3)) * 1024 + ssl * 8;

#define STGA(d, rowoff, koff) GLL16(Ag + (size_t)(rowoff) * 1024 + (koff), &As[d][(rowoff) * 64 + tid * 8])
#define STGB(d, rowoff, koff) GLL16(Bg + (size_t)(rowoff) * 1024 + (koff), &Bs[d][(rowoff) * 64 + tid * 8])
#define STAGE_AB(d, koff) do { STGA(d,0,koff); STGA(d,64,koff); \
                               STGB(d,0,koff); STGB(d,64,koff); STGB(d,128,koff); } while (0)

    f32x4 acc[4][3];
#pragma unroll
    for (int mi = 0; mi < 4; ++mi)
#pragma unroll
        for (int ni = 0; ni < 3; ++ni) acc[mi][ni] = (f32x4)0.f;

    const int swz  = q15 >> 1;
    const int arow = (wr * 64 + q15) * 64;
    const int brow = (wc * 48 + q15) * 64;
    const int s0o  = (p ^ swz) * 8;          // ks=0 slot (shorts)
    const int s1o  = ((4 + p) ^ swz) * 8;    // ks=1

    STAGE_AB(0, 0);
    STAGE_AB(1, 64);
    WAITV(5); SBAR(); SCHED0();              // kt0 landed; kt1's 5 in flight

#pragma unroll
    for (int kt = 0; kt < 16; ++kt) {
        const int par = kt & 1;
        const short* asd = &As[par][0];
        const short* bsd = &Bs[par][0];
        bf16x8 af[4][2], bf[3][2];

        // ---- ph1: ds_read all frags (8 A + 6 B b128); lgkm0; SBAR
#pragma unroll
        for (int mi = 0; mi < 4; ++mi) {
            af[mi][0] = *(const bf16x8*)(asd + arow + mi * 1024 + s0o);
            af[mi][1] = *(const bf16x8*)(asd + arow + mi * 1024 + s1o);
        }
#pragma unroll
        for (int ni = 0; ni < 3; ++ni) {
            bf[ni][0] = *(const bf16x8*)(bsd + brow + ni * 1024 + s0o);
            bf[ni][1] = *(const bf16x8*)(bsd + brow + ni * 1024 + s1o);
        }
        WAITL0(); SBAR(); SCHED0();          // dbuf[par] free block-wide

        // ---- ph2: stage kt+2 -> dbuf[par]; MFMA 4x3x2; gate; SBAR
        if (kt < 14) STAGE_AB(par, (kt + 2) * 64);
        __builtin_amdgcn_s_setprio(1);
#pragma unroll
        for (int mi = 0; mi < 4; ++mi)
#pragma unroll
            for (int ni = 0; ni < 3; ++ni) {
                acc[mi][ni] = __builtin_amdgcn_mfma_f32_16x16x32_bf16(af[mi][0], bf[ni][0], acc[mi][ni], 0, 0, 0);
                acc[mi][ni] = __builtin_amdgcn_mfma_f32_16x16x32_bf16(af[mi][1], bf[ni][1], acc[mi][ni], 0, 0, 0);
            }
        __builtin_amdgcn_s_setprio(0);
        SCHED0();
        if (kt < 14)       { WAITV(5); SBAR(); SCHED0(); }  // retires kt+1's 5
        else if (kt == 14) { WAITV(0); SBAR(); SCHED0(); }  // drain for kt15
    }
#undef STGA
#undef STGB
#undef STAGE_AB

    // epilogue: head h = tni; scatter q/k [bh][s][d], v^T [bh][d][s]
#pragma unroll
    for (int mi = 0; mi < 4; ++mi) {
#pragma unroll
        for (int ni = 0; ni < 3; ++ni) {
            const int c    = wc * 48 + ni * 16 + q15;   // 0..191 within head
            const int part = c >> 6;
            const int dd   = c & 63;
            const int row0 = tm + wr * 64 + mi * 16 + p * 4;
            const float bv = bias[tn + c];
            const size_t pbase = (size_t)part * PARTSZ;
#pragma unroll
            for (int r = 0; r < 4; ++r) {
                const int row = row0 + r;               // b*2048 + s
                const int b   = row >> 11;
                const int s   = row & 2047;
                const size_t hb = pbase + ((((size_t)b << 4) + tni) << 17);
                const size_t addr = (part == 2)
                    ? hb + ((size_t)dd << 11) + s
                    : hb + ((size_t)s << 6) + dd;
                dst[addr] = f2bf(acc[mi][ni][r] + bv);
            }
        }
    }
}

// ================= GEMM2: output projection, r11-style (r13) ========
// C[4096,1024] = A[4096,1024] * B[1024,1024]^T + bias (f32 out).
// Tile 64x128, BK=64, grid 512 = 2/CU, LDS 48 KB 2dbuf, 4 waves 1M x 4N.
// r14: XCD remap -- each XCD gets 8 tmi x all-8 tni (A 1MB + B 2MB in L2).
// Bijective: tmi = xcd*8 + (k&7), tni = k>>3.
__global__ __launch_bounds__(256, 4)
void gemm2_k(const short* __restrict__ A, const short* __restrict__ Bm,
             const float* __restrict__ bias, float* __restrict__ C)
{
    __shared__ short As[2][4096];    // 2 dbuf x [64][64] bf16 = 16 KB
    __shared__ short Bs[2][8192];    // 2 dbuf x [128][64] bf16 = 32 KB
    const int tid  = threadIdx.x;
    const int lane = tid & 63;
    const int wc   = tid >> 6;       // wave = n-quarter (1M x 4N)
    const int q15 = lane & 15, p = lane >> 4;

    const int xcd = blockIdx.x & 7;
    const int kk  = blockIdx.x >> 3;         // 0..63
    const int tm = ((xcd << 3) | (kk & 7)) << 6;   // tmi 0..63
    const int tn = (kk >> 3) << 7;                 // tni 0..7

    const int ssl = (tid & 7) ^ ((tid >> 4) & 7);
    const short* Ag = A  + (size_t)(tm + (tid >> 3)) * 1024 + ssl * 8;
    const short* Bg = Bm + (size_t)(tn + (tid >> 3)) * 1024 + ssl * 8;

#define STGA2(d, rowoff, koff) GLL16(Ag + (size_t)(rowoff) * 1024 + (koff), &As[d][(rowoff) * 64 + tid * 8])
#define STGB2(d, rowoff, koff) GLL16(Bg + (size_t)(rowoff) * 1024 + (koff), &Bs[d][(rowoff) * 64 + tid * 8])
#define STAGE2_AB(d, koff) do { STGA2(d,0,koff); STGA2(d,32,koff); \
                                STGB2(d,0,koff); STGB2(d,32,koff); \
                                STGB2(d,64,koff); STGB2(d,96,koff); } while (0)

    f32x4 acc[4][2];
#pragma unroll
    for (int mi = 0; mi < 4; ++mi)
#pragma unroll
        for (int ni = 0; ni < 2; ++ni) acc[mi][ni] = (f32x4)0.f;

    const int swz  = q15 >> 1;
    const int arow = q15 * 64;
    const int brow = (wc * 32 + q15) * 64;
    const int s0o  = (p ^ swz) * 8;
    const int s1o  = ((4 + p) ^ swz) * 8;

    STAGE2_AB(0, 0);
    STAGE2_AB(1, 64);
    WAITV(6); SBAR(); SCHED0();              // kt0 landed; kt1's 6 in flight

#pragma unroll
    for (int kt = 0; kt < 16; ++kt) {
        const int par = kt & 1;
        const short* asd = &As[par][0];
        const short* bsd = &Bs[par][0];
        bf16x8 af[4][2], bf[2][2];

        // ---- ph1: ds_read all frags (8 A + 4 B b128); lgkm0; SBAR
#pragma unroll
        for (int mi = 0; mi < 4; ++mi) {
            af[mi][0] = *(const bf16x8*)(asd + arow + mi * 1024 + s0o);
            af[mi][1] = *(const bf16x8*)(asd + arow + mi * 1024 + s1o);
        }
#pragma unroll
        for (int ni = 0; ni < 2; ++ni) {
            bf[ni][0] = *(const bf16x8*)(bsd + brow + ni * 1024 + s0o);
            bf[ni][1] = *(const bf16x8*)(bsd + brow + ni * 1024 + s1o);
        }
        WAITL0(); SBAR(); SCHED0();          // dbuf[par] free block-wide

        // ---- ph2: stage kt+2 -> dbuf[par]; MFMA 4x2x2; gate; SBAR
        if (kt < 14) STAGE2_AB(par, (kt + 2) * 64);
        __builtin_amdgcn_s_setprio(1);
#pragma unroll
        for (int mi = 0; mi < 4; ++mi)
#pragma unroll
            for (int ni = 0; ni < 2; ++ni) {
                acc[mi][ni] = __builtin_amdgcn_mfma_f32_16x16x32_bf16(af[mi][0], bf[ni][0], acc[mi][ni], 0, 0, 0);
                acc[mi][ni] = __builtin_amdgcn_mfma_f32_16x16x32_bf16(af[mi][1], bf[ni][1], acc[mi][ni], 0, 0, 0);
            }
        __builtin_amdgcn_s_setprio(0);
        SCHED0();
        if (kt < 14)       { WAITV(6); SBAR(); SCHED0(); }  // retires kt+1's 6
        else if (kt == 14) { WAITV(0); SBAR(); SCHED0(); }  // drain for kt15
    }
#undef STGA2
#undef STGB2
#undef STAGE2_AB

#pragma unroll
    for (int mi = 0; mi < 4; ++mi) {
#pragma unroll
        for (int ni = 0; ni < 2; ++ni) {
            const int col  = tn + wc * 32 + ni * 16 + q15;
            const int row0 = tm + mi * 16 + p * 4;
            const float bv = bias[col];
#pragma unroll
            for (int r = 0; r < 4; ++r)
                C[(size_t)(row0 + r) * 1024 + col] = acc[mi][ni][r] + bv;
        }
    }
}

// ---------------- sliding-window attention via MFMA (r4-verified) ----------------
// r14: XCD remap -- each XCD gets 4 bh x all-32 tiles (q/k/v ~3MB L2-resident).
// Bijective: bh = xcd*4 + (k&3), tile = k>>2.
__global__ __launch_bounds__(256)
void swattn4_k(const short* __restrict__ qkvb, short* __restrict__ ctx)
{
    __shared__ short Ks[96 * 64];
    __shared__ short Vt[64 * 104];
    const int tid  = threadIdx.x;
    const int lane = tid & 63;
    const int w    = tid >> 6;
    const int q15  = lane & 15;
    const int p    = lane >> 4;
    const int xcd  = blockIdx.x & 7;
    const int kk   = blockIdx.x >> 3;          // 0..127
    const int bh   = (xcd << 2) | (kk & 3);    // 0..31
    const int tile = kk >> 2;                  // 0..31
    const int b    = bh >> 4, h = bh & 15;
    const int s0   = tile * 64;
    const short* qbase  = qkvb + ((size_t)bh << 17);
    const short* kbase  = qbase + PARTSZ;
    const short* vtbase = qbase + 2 * PARTSZ;

#pragma unroll
    for (int c = 0; c < 3; ++c) {
        const int idx = c * 256 + tid;
        const int row = idx >> 3;
        const int sli = idx & 7;
        const int pos = s0 - 16 + row;
        bf16x8 kv = (bf16x8)0;
        if (pos >= 0 && pos < SEQ)
            kv = *(const bf16x8*)(kbase + (size_t)pos * 64 + sli * 8);
        *(bf16x8*)(Ks + row * 64 + ((sli ^ (row & 7)) << 3)) = kv;
    }
#pragma unroll
    for (int c = 0; c < 4; ++c) {
        const int idx = c * 256 + tid;
        const int d   = idx >> 4;
        const int sli = idx & 15;
        if (sli < 12) {
            const int pos = s0 - 16 + sli * 8;
            bf16x8 vv = (bf16x8)0;
            if (pos >= 0 && pos <= SEQ - 8)
                vv = *(const bf16x8*)(vtbase + (size_t)d * SEQ + pos);
            *(bf16x8*)(Vt + d * 104 + sli * 8) = vv;
        }
    }
    __syncthreads();

    const int qrow = s0 + w * 16 + q15;
    const bf16x8 qf0 = *(const bf16x8*)(qbase + (size_t)qrow * 64 + p * 8);
    const bf16x8 qf1 = *(const bf16x8*)(qbase + (size_t)qrow * 64 + 32 + p * 8);

    f32x4 accs[6];
#pragma unroll
    for (int t = 0; t < 6; ++t) accs[t] = (f32x4)0.f;
#pragma unroll
    for (int t = 0; t < 6; ++t) {
        const int row = t * 16 + q15;
        const int sw  = row & 7;
        const bf16x8 kf0 = *(const bf16x8*)(Ks + row * 64 + ((p ^ sw) << 3));
        const bf16x8 kf1 = *(const bf16x8*)(Ks + row * 64 + (((p + 4) ^ sw) << 3));
        accs[t] = __builtin_amdgcn_mfma_f32_16x16x32_bf16(kf0, qf0, accs[t], 0, 0, 0);
        accs[t] = __builtin_amdgcn_mfma_f32_16x16x32_bf16(kf1, qf1, accs[t], 0, 0, 0);
    }

    const int qloc = w * 16 + q15;
    float m = -1e30f;
#pragma unroll
    for (int t = 0; t < 6; ++t)
#pragma unroll
        for (int r = 0; r < 4; ++r) {
            const int n = t * 16 + p * 4 + r;
            const bool valid = (n >= qloc) && (n <= qloc + 32);
            const float v = valid ? accs[t][r] * 0.125f : -1e30f;
            accs[t][r] = v;
            m = fmaxf(m, v);
        }
    m = fmaxf(m, __shfl_xor(m, 16));
    m = fmaxf(m, __shfl_xor(m, 32));
    float sum = 0.f;
#pragma unroll
    for (int t = 0; t < 6; ++t)
#pragma unroll
        for (int r = 0; r < 4; ++r) {
            const float e = __expf(accs[t][r] - m);
            accs[t][r] = e;
            sum += e;
        }
    sum += __shfl_xor(sum, 16);
    sum += __shfl_xor(sum, 32);
    const float inv = 1.f / sum;

    uint32_t pk[6][2];
#pragma unroll
    for (int t = 0; t < 6; ++t)
#pragma unroll
        for (int rp = 0; rp < 2; ++rp) {
            const float lo = accs[t][2 * rp] * inv;
            const float hi = accs[t][2 * rp + 1] * inv;
            uint32_t o;
            asm("v_cvt_pk_bf16_f32 %0, %1, %2" : "=v"(o) : "v"(lo), "v"(hi));
            pk[t][rp] = o;
        }
    uint32_t afu[3][4];
#pragma unroll
    for (int t = 0; t < 6; ++t)
#pragma unroll
        for (int rp = 0; rp < 2; ++rp)
#pragma unroll
            for (int bb = 0; bb < 2; ++bb) {
                const int src = q15 + (((2 * p + bb) & 3) << 4);
                const uint32_t v = __shfl((int)pk[t][rp], src);
                if ((t & 1) == (p >> 1))
                    afu[t >> 1][2 * bb + rp] = v;
            }
    union U { uint32_t u[4]; bf16x8 v; };
    U u0, u1, u2;
#pragma unroll
    for (int f = 0; f < 4; ++f) { u0.u[f] = afu[0][f]; u1.u[f] = afu[1][f]; u2.u[f] = afu[2][f]; }
    const bf16x8 af0 = u0.v, af1 = u1.v, af2 = u2.v;

    f32x4 accp[4];
#pragma unroll
    for (int dt = 0; dt < 4; ++dt) accp[dt] = (f32x4)0.f;
#pragma unroll
    for (int dt = 0; dt < 4; ++dt) {
        const short* vr = Vt + (dt * 16 + q15) * 104 + p * 8;
        const bf16x8 vf0 = *(const bf16x8*)(vr);
        const bf16x8 vf1 = *(const bf16x8*)(vr + 32);
        const bf16x8 vf2 = *(const bf16x8*)(vr + 64);
        accp[dt] = __builtin_amdgcn_mfma_f32_16x16x32_bf16(af0, vf0, accp[dt], 0, 0, 0);
        accp[dt] = __builtin_amdgcn_mfma_f32_16x16x32_bf16(af1, vf1, accp[dt], 0, 0, 0);
        accp[dt] = __builtin_amdgcn_mfma_f32_16x16x32_bf16(af2, vf2, accp[dt], 0, 0, 0);
    }

#pragma unroll
    for (int dt = 0; dt < 4; ++dt) {
        const int d = dt * 16 + q15;
#pragma unroll
        for (int r = 0; r < 4; ++r) {
            const int s = s0 + w * 16 + p * 4 + r;
            ctx[(((size_t)(b * SEQ + s)) << 10) + h * 64 + d] = f2bf(accp[dt][r]);
        }
    }
}

// ---------------- launch ----------------
extern "C" void kernel_launch(void* const* d_in, const int* in_sizes, int n_in,
                              void* d_out, int out_size, void* d_ws, size_t ws_size,
                              hipStream_t stream)
{
    const float* x     = (const float*)d_in[0];
    const float* w_qkv = (const float*)d_in[1];
    const float* b_qkv = (const float*)d_in[2];
    const float* w_out = (const float*)d_in[3];
    const float* b_out = (const float*)d_in[4];
    float* out = (float*)d_out;

    char* ws = (char*)d_ws;
    short* x_bf    = (short*)(ws);                       // 8 MB
    short* wqkv_bf = (short*)(ws + (8ull  << 20));       // 6 MB
    short* wout_bf = (short*)(ws + (14ull << 20));       // 2 MB
    short* qkvb    = (short*)(ws + (16ull << 20));       // 24 MB: q,k [bh][s][d]; v^T [bh][d][s]
    short* ctx     = (short*)(ws + (48ull << 20));       // 8 MB

    cvt3_k<<<dim3(4096), 256, 0, stream>>>(x, x_bf, w_qkv, wqkv_bf, w_out, wout_bf);

    gemm1_k<<<dim3(512), 512, 0, stream>>>(x_bf, wqkv_bf, b_qkv, qkvb);

    swattn4_k<<<dim3((SEQ / 64) * BATCH * NHEADS), 256, 0, stream>>>(qkvb, (short*)ctx);

    gemm2_k<<<dim3(512), 256, 0, stream>>>(ctx, wout_bf, b_out, out);
}

// Round 15
// 65.743 us; speedup vs baseline: 1.1898x; 1.0141x over previous
//
#include <hip/hip_runtime.h>
#include <stdint.h>

#define NHEADS 16
#define HDIM 64
#define WIN 33
#define BATCH 2
#define SEQ 2048
#define MROWS (BATCH*SEQ)   // 4096
#define PARTSZ (BATCH*NHEADS*SEQ*HDIM)  // 4194304

using f32x4 = __attribute__((ext_vector_type(4))) float;
using bf16x8 = __attribute__((ext_vector_type(8))) short;

__device__ inline short f2bf(float f) {
    union { float f; uint32_t u; } c; c.f = f;
    uint32_t u = c.u;
    uint32_t r = (u + 0x7fffu + ((u >> 16) & 1u)) >> 16;
    return (short)(uint16_t)r;
}

#define GLL16(g, l) __builtin_amdgcn_global_load_lds( \
        (const __attribute__((address_space(1))) void*)(g), \
        (__attribute__((address_space(3))) void*)(l), 16, 0, 0)
#define WAITV(n)  asm volatile("s_waitcnt vmcnt(" #n ")" ::: "memory")
#define WAITL0()  asm volatile("s_waitcnt lgkmcnt(0)" ::: "memory")
#define SBAR()    __builtin_amdgcn_s_barrier()
#define SCHED0()  __builtin_amdgcn_sched_barrier(0)

// ---------------- fused f32->bf16 for x, w_qkv, w_out ----------------
__global__ __launch_bounds__(256)
void cvt3_k(const float* __restrict__ x,  short* __restrict__ xb,
            const float* __restrict__ w1, short* __restrict__ w1b,
            const float* __restrict__ w2, short* __restrict__ w2b)
{
    const int i = blockIdx.x * 256 + threadIdx.x;
    const float* src; short* dstp; int off;
    if (i < 524288)      { src = x;  dstp = xb;  off = i; }
    else if (i < 917504) { src = w1; dstp = w1b; off = i - 524288; }
    else                 { src = w2; dstp = w2b; off = i - 917504; }
    const f32x4 v0 = *(const f32x4*)(src + (size_t)off * 8);
    const f32x4 v1 = *(const f32x4*)(src + (size_t)off * 8 + 4);
    bf16x8 o;
    o[0] = f2bf(v0[0]); o[1] = f2bf(v0[1]); o[2] = f2bf(v0[2]); o[3] = f2bf(v0[3]);
    o[4] = f2bf(v1[0]); o[5] = f2bf(v1[1]); o[6] = f2bf(v1[2]); o[7] = f2bf(v1[3]);
    *(bf16x8*)(dstp + (size_t)off * 8) = o;
}

// ================= GEMM1: qkv projection, 128x192, 4 waves of 64x96 =========
// C[4096,3072] = A[4096,1024] * B[3072,1024]^T + bias -> bf16 scatter.
// r15: same 128x192 block tile / 80KB LDS / 2 blocks/CU / 2-phase counted-
// vmcnt schedule as r11-r14, but 4 waves of 64x96 instead of 8 of 64x48:
// LDS bytes/FLOP ~ (Mw+Nw)/(Mw*Nw) -> 160/6144 vs 112/3072 = -29% LDS reads
// (per-CU 224 -> 160 b128/kt). Occupancy 2 waves/SIMD (vs 4) -- the two
// independent barrier domains per CU (r11's key) are retained.
// Block = 256 threads. Staging: 10 GLL16/kt (A 4 + B 6; 256thr x 16B = 32
// rows/call); steady WAITV(10) retires exactly kt+1's loads. VGPR ~195
// (acc[4][6]=96 + frags 80) < 256 at launch_bounds(256,2): no spill.
// XCD 2-D remap (r14) and slot swizzle (0 conflicts) unchanged;
// (row>>1)&7 == q15>>1 still holds (96*wc, 16*ni are 0 mod 16).
__global__ __launch_bounds__(256, 2)
void gemm1_k(const short* __restrict__ A, const short* __restrict__ Bm,
             const float* __restrict__ bias, short* __restrict__ dst)
{
    __shared__ short As[2][8192];    // 2 dbuf x [128][64] bf16 = 32 KB
    __shared__ short Bs[2][12288];   // 2 dbuf x [192][64] bf16 = 48 KB
    const int tid  = threadIdx.x;
    const int lane = tid & 63;
    const int wv   = tid >> 6;               // 0..3
    const int wr = wv >> 1, wc = wv & 1;     // 2M x 2N waves, 64x96 each
    const int q15 = lane & 15, p = lane >> 4;

    const int xcd = blockIdx.x & 7;          // HW XCD = blockIdx % 8
    const int kk  = blockIdx.x >> 3;         // 0..63 within-XCD index
    const int tmi = (kk & 7) | ((xcd & 3) << 3);   // 0..31
    const int tni = (kk >> 3) | ((xcd >> 2) << 3); // 0..15
    const int tm = tmi << 7;                 // m-tile base (128)
    const int tn = tni * 192;                // n-tile base = head tni

    // staging: one GLL16 (256 thr) = 32 rows x 128B; source slot pre-swizzled
    const int ssl = (tid & 7) ^ ((tid >> 4) & 7);
    const short* Ag = A  + (size_t)(tm + (tid >> 3)) * 1024 + ssl * 8;
    const short* Bg = Bm + (size_t)(tn + (tid >> 3)) * 1024 + ssl * 8;

#define STGA(d, rowoff, koff) GLL16(Ag + (size_t)(rowoff) * 1024 + (koff), &As[d][(rowoff) * 64 + tid * 8])
#define STGB(d, rowoff, koff) GLL16(Bg + (size_t)(rowoff) * 1024 + (koff), &Bs[d][(rowoff) * 64 + tid * 8])
#define STAGE_AB(d, koff) do { \
        STGA(d,0,koff); STGA(d,32,koff); STGA(d,64,koff); STGA(d,96,koff); \
        STGB(d,0,koff); STGB(d,32,koff); STGB(d,64,koff); \
        STGB(d,96,koff); STGB(d,128,koff); STGB(d,160,koff); } while (0)

    f32x4 acc[4][6];
#pragma unroll
    for (int mi = 0; mi < 4; ++mi)
#pragma unroll
        for (int ni = 0; ni < 6; ++ni) acc[mi][ni] = (f32x4)0.f;

    // fragment reads: A row = wr*64 + mi*16 + q15; B row = wc*96 + ni*16 + q15.
    const int swz  = q15 >> 1;
    const int arow = (wr * 64 + q15) * 64;
    const int brow = (wc * 96 + q15) * 64;
    const int s0o  = (p ^ swz) * 8;          // ks=0 slot (shorts)
    const int s1o  = ((4 + p) ^ swz) * 8;    // ks=1

    // prologue: kt0 -> d0 (10 loads), kt1 -> d1 (10 loads)
    STAGE_AB(0, 0);
    STAGE_AB(1, 64);
    WAITV(10); SBAR(); SCHED0();             // kt0 landed; kt1's 10 in flight

#pragma unroll
    for (int kt = 0; kt < 16; ++kt) {
        const int par = kt & 1;
        const short* asd = &As[par][0];
        const short* bsd = &Bs[par][0];
        bf16x8 af[4][2], bf[6][2];

        // ---- ph1: ds_read all frags (8 A + 12 B b128); lgkm0; SBAR
#pragma unroll
        for (int mi = 0; mi < 4; ++mi) {
            af[mi][0] = *(const bf16x8*)(asd + arow + mi * 1024 + s0o);
            af[mi][1] = *(const bf16x8*)(asd + arow + mi * 1024 + s1o);
        }
#pragma unroll
        for (int ni = 0; ni < 6; ++ni) {
            bf[ni][0] = *(const bf16x8*)(bsd + brow + ni * 1024 + s0o);
            bf[ni][1] = *(const bf16x8*)(bsd + brow + ni * 1024 + s1o);
        }
        WAITL0(); SBAR(); SCHED0();          // dbuf[par] free block-wide

        // ---- ph2: stage kt+2 -> dbuf[par]; MFMA 4x6x2; gate; SBAR
        if (kt < 14) STAGE_AB(par, (kt + 2) * 64);
        __builtin_amdgcn_s_setprio(1);
#pragma unroll
        for (int mi = 0; mi < 4; ++mi)
#pragma unroll
            for (int ni = 0; ni < 6; ++ni) {
                acc[mi][ni] = __builtin_amdgcn_mfma_f32_16x16x32_bf16(af[mi][0], bf[ni][0], acc[mi][ni], 0, 0, 0);
                acc[mi][ni] = __builtin_amdgcn_mfma_f32_16x16x32_bf16(af[mi][1], bf[ni][1], acc[mi][ni], 0, 0, 0);
            }
        __builtin_amdgcn_s_setprio(0);
        SCHED0();
        if (kt < 14)       { WAITV(10); SBAR(); SCHED0(); }  // retires kt+1's 10
        else if (kt == 14) { WAITV(0);  SBAR(); SCHED0(); }  // drain for kt15
    }
#undef STGA
#undef STGB
#undef STAGE_AB

    // epilogue: head h = tni; scatter q/k [bh][s][d], v^T [bh][d][s]
#pragma unroll
    for (int mi = 0; mi < 4; ++mi) {
#pragma unroll
        for (int ni = 0; ni < 6; ++ni) {
            const int c    = wc * 96 + ni * 16 + q15;   // 0..191 within head
            const int part = c >> 6;
            const int dd   = c & 63;
            const int row0 = tm + wr * 64 + mi * 16 + p * 4;
            const float bv = bias[tn + c];
            const size_t pbase = (size_t)part * PARTSZ;
#pragma unroll
            for (int r = 0; r < 4; ++r) {
                const int row = row0 + r;               // b*2048 + s
                const int b   = row >> 11;
                const int s   = row & 2047;
                const size_t hb = pbase + ((((size_t)b << 4) + tni) << 17);
                const size_t addr = (part == 2)
                    ? hb + ((size_t)dd << 11) + s
                    : hb + ((size_t)s << 6) + dd;
                dst[addr] = f2bf(acc[mi][ni][r] + bv);
            }
        }
    }
}

// ================= GEMM2: output projection, r11-style (r13/r14) ========
// C[4096,1024] = A[4096,1024] * B[1024,1024]^T + bias (f32 out).
// Tile 64x128, BK=64, grid 512 = 2/CU, LDS 48 KB 2dbuf, 4 waves 1M x 4N.
// XCD remap: tmi = xcd*8 + (k&7), tni = k>>3 (A 1MB + B 2MB in L2).
__global__ __launch_bounds__(256, 4)
void gemm2_k(const short* __restrict__ A, const short* __restrict__ Bm,
             const float* __restrict__ bias, float* __restrict__ C)
{
    __shared__ short As[2][4096];    // 2 dbuf x [64][64] bf16 = 16 KB
    __shared__ short Bs[2][8192];    // 2 dbuf x [128][64] bf16 = 32 KB
    const int tid  = threadIdx.x;
    const int lane = tid & 63;
    const int wc   = tid >> 6;       // wave = n-quarter (1M x 4N)
    const int q15 = lane & 15, p = lane >> 4;

    const int xcd = blockIdx.x & 7;
    const int kk  = blockIdx.x >> 3;         // 0..63
    const int tm = ((xcd << 3) | (kk & 7)) << 6;   // tmi 0..63
    const int tn = (kk >> 3) << 7;                 // tni 0..7

    const int ssl = (tid & 7) ^ ((tid >> 4) & 7);
    const short* Ag = A  + (size_t)(tm + (tid >> 3)) * 1024 + ssl * 8;
    const short* Bg = Bm + (size_t)(tn + (tid >> 3)) * 1024 + ssl * 8;

#define STGA2(d, rowoff, koff) GLL16(Ag + (size_t)(rowoff) * 1024 + (koff), &As[d][(rowoff) * 64 + tid * 8])
#define STGB2(d, rowoff, koff) GLL16(Bg + (size_t)(rowoff) * 1024 + (koff), &Bs[d][(rowoff) * 64 + tid * 8])
#define STAGE2_AB(d, koff) do { STGA2(d,0,koff); STGA2(d,32,koff); \
                                STGB2(d,0,koff); STGB2(d,32,koff); \
                                STGB2(d,64,koff); STGB2(d,96,koff); } while (0)

    f32x4 acc[4][2];
#pragma unroll
    for (int mi = 0; mi < 4; ++mi)
#pragma unroll
        for (int ni = 0; ni < 2; ++ni) acc[mi][ni] = (f32x4)0.f;

    const int swz  = q15 >> 1;
    const int arow = q15 * 64;
    const int brow = (wc * 32 + q15) * 64;
    const int s0o  = (p ^ swz) * 8;
    const int s1o  = ((4 + p) ^ swz) * 8;

    STAGE2_AB(0, 0);
    STAGE2_AB(1, 64);
    WAITV(6); SBAR(); SCHED0();              // kt0 landed; kt1's 6 in flight

#pragma unroll
    for (int kt = 0; kt < 16; ++kt) {
        const int par = kt & 1;
        const short* asd = &As[par][0];
        const short* bsd = &Bs[par][0];
        bf16x8 af[4][2], bf[2][2];

        // ---- ph1: ds_read all frags (8 A + 4 B b128); lgkm0; SBAR
#pragma unroll
        for (int mi = 0; mi < 4; ++mi) {
            af[mi][0] = *(const bf16x8*)(asd + arow + mi * 1024 + s0o);
            af[mi][1] = *(const bf16x8*)(asd + arow + mi * 1024 + s1o);
        }
#pragma unroll
        for (int ni = 0; ni < 2; ++ni) {
            bf[ni][0] = *(const bf16x8*)(bsd + brow + ni * 1024 + s0o);
            bf[ni][1] = *(const bf16x8*)(bsd + brow + ni * 1024 + s1o);
        }
        WAITL0(); SBAR(); SCHED0();          // dbuf[par] free block-wide

        // ---- ph2: stage kt+2 -> dbuf[par]; MFMA 4x2x2; gate; SBAR
        if (kt < 14) STAGE2_AB(par, (kt + 2) * 64);
        __builtin_amdgcn_s_setprio(1);
#pragma unroll
        for (int mi = 0; mi < 4; ++mi)
#pragma unroll
            for (int ni = 0; ni < 2; ++ni) {
                acc[mi][ni] = __builtin_amdgcn_mfma_f32_16x16x32_bf16(af[mi][0], bf[ni][0], acc[mi][ni], 0, 0, 0);
                acc[mi][ni] = __builtin_amdgcn_mfma_f32_16x16x32_bf16(af[mi][1], bf[ni][1], acc[mi][ni], 0, 0, 0);
            }
        __builtin_amdgcn_s_setprio(0);
        SCHED0();
        if (kt < 14)       { WAITV(6); SBAR(); SCHED0(); }  // retires kt+1's 6
        else if (kt == 14) { WAITV(0); SBAR(); SCHED0(); }  // drain for kt15
    }
#undef STGA2
#undef STGB2
#undef STAGE2_AB

#pragma unroll
    for (int mi = 0; mi < 4; ++mi) {
#pragma unroll
        for (int ni = 0; ni < 2; ++ni) {
            const int col  = tn + wc * 32 + ni * 16 + q15;
            const int row0 = tm + mi * 16 + p * 4;
            const float bv = bias[col];
#pragma unroll
            for (int r = 0; r < 4; ++r)
                C[(size_t)(row0 + r) * 1024 + col] = acc[mi][ni][r] + bv;
        }
    }
}

// ---------------- sliding-window attention via MFMA (r4-verified) ----------------
// XCD remap: bh = xcd*4 + (k&3), tile = k>>2 (q/k/v ~3MB L2-resident).
__global__ __launch_bounds__(256)
void swattn4_k(const short* __restrict__ qkvb, short* __restrict__ ctx)
{
    __shared__ short Ks[96 * 64];
    __shared__ short Vt[64 * 104];
    const int tid  = threadIdx.x;
    const int lane = tid & 63;
    const int w    = tid >> 6;
    const int q15  = lane & 15;
    const int p    = lane >> 4;
    const int xcd  = blockIdx.x & 7;
    const int kk   = blockIdx.x >> 3;          // 0..127
    const int bh   = (xcd << 2) | (kk & 3);    // 0..31
    const int tile = kk >> 2;                  // 0..31
    const int b    = bh >> 4, h = bh & 15;
    const int s0   = tile * 64;
    const short* qbase  = qkvb + ((size_t)bh << 17);
    const short* kbase  = qbase + PARTSZ;
    const short* vtbase = qbase + 2 * PARTSZ;

#pragma unroll
    for (int c = 0; c < 3; ++c) {
        const int idx = c * 256 + tid;
        const int row = idx >> 3;
        const int sli = idx & 7;
        const int pos = s0 - 16 + row;
        bf16x8 kv = (bf16x8)0;
        if (pos >= 0 && pos < SEQ)
            kv = *(const bf16x8*)(kbase + (size_t)pos * 64 + sli * 8);
        *(bf16x8*)(Ks + row * 64 + ((sli ^ (row & 7)) << 3)) = kv;
    }
#pragma unroll
    for (int c = 0; c < 4; ++c) {
        const int idx = c * 256 + tid;
        const int d   = idx >> 4;
        const int sli = idx & 15;
        if (sli < 12) {
            const int pos = s0 - 16 + sli * 8;
            bf16x8 vv = (bf16x8)0;
            if (pos >= 0 && pos <= SEQ - 8)
                vv = *(const bf16x8*)(vtbase + (size_t)d * SEQ + pos);
            *(bf16x8*)(Vt + d * 104 + sli * 8) = vv;
        }
    }
    __syncthreads();

    const int qrow = s0 + w * 16 + q15;
    const bf16x8 qf0 = *(const bf16x8*)(qbase + (size_t)qrow * 64 + p * 8);
    const bf16x8 qf1 = *(const bf16x8*)(qbase + (size_t)qrow * 64 + 32 + p * 8);

    f32x4 accs[6];
#pragma unroll
    for (int t = 0; t < 6; ++t) accs[t] = (f32x4)0.f;
#pragma unroll
    for (int t = 0; t < 6; ++t) {
        const int row = t * 16 + q15;
        const int sw  = row & 7;
        const bf16x8 kf0 = *(const bf16x8*)(Ks + row * 64 + ((p ^ sw) << 3));
        const bf16x8 kf1 = *(const bf16x8*)(Ks + row * 64 + (((p + 4) ^ sw) << 3));
        accs[t] = __builtin_amdgcn_mfma_f32_16x16x32_bf16(kf0, qf0, accs[t], 0, 0, 0);
        accs[t] = __builtin_amdgcn_mfma_f32_16x16x32_bf16(kf1, qf1, accs[t], 0, 0, 0);
    }

    const int qloc = w * 16 + q15;
    float m = -1e30f;
#pragma unroll
    for (int t = 0; t < 6; ++t)
#pragma unroll
        for (int r = 0; r < 4; ++r) {
            const int n = t * 16 + p * 4 + r;
            const bool valid = (n >= qloc) && (n <= qloc + 32);
            const float v = valid ? accs[t][r] * 0.125f : -1e30f;
            accs[t][r] = v;
            m = fmaxf(m, v);
        }
    m = fmaxf(m, __shfl_xor(m, 16));
    m = fmaxf(m, __shfl_xor(m, 32));
    float sum = 0.f;
#pragma unroll
    for (int t = 0; t < 6; ++t)
#pragma unroll
        for (int r = 0; r < 4; ++r) {
            const float e = __expf(accs[t][r] - m);
            accs[t][r] = e;
            sum += e;
        }
    sum += __shfl_xor(sum, 16);
    sum += __shfl_xor(sum, 32);
    const float inv = 1.f / sum;

    uint32_t pk[6][2];
#pragma unroll
    for (int t = 0; t < 6; ++t)
#pragma unroll
        for (int rp = 0; rp < 2; ++rp) {
            const float lo = accs[t][2 * rp] * inv;
            const float hi = accs[t][2 * rp + 1] * inv;
            uint32_t o;
            asm("v_cvt_pk_bf16_f32 %0, %1, %2" : "=v"(o) : "v"(lo), "v"(hi));
            pk[t][rp] = o;
        }
    uint32_t afu[3][4];
#pragma unroll
    for (int t = 0; t < 6; ++t)
#pragma unroll
        for (int rp = 0; rp < 2; ++rp)
#pragma unroll
            for (int bb = 0; bb < 2; ++bb) {
                const int src = q15 + (((2 * p + bb) & 3) << 4);
                const uint32_t v = __shfl((int)pk[t][rp], src);
                if ((t & 1) == (p >> 1))
                    afu[t >> 1][2 * bb + rp] = v;
            }
    union U { uint32_t u[4]; bf16x8 v; };
    U u0, u1, u2;
#pragma unroll
    for (int f = 0; f < 4; ++f) { u0.u[f] = afu[0][f]; u1.u[f] = afu[1][f]; u2.u[f] = afu[2][f]; }
    const bf16x8 af0 = u0.v, af1 = u1.v, af2 = u2.v;

    f32x4 accp[4];
#pragma unroll
    for (int dt = 0; dt < 4; ++dt) accp[dt] = (f32x4)0.f;
#pragma unroll
    for (int dt = 0; dt < 4; ++dt) {
        const short* vr = Vt + (dt * 16 + q15) * 104 + p * 8;
        const bf16x8 vf0 = *(const bf16x8*)(vr);
        const bf16x8 vf1 = *(const bf16x8*)(vr + 32);
        const bf16x8 vf2 = *(const bf16x8*)(vr + 64);
        accp[dt] = __builtin_amdgcn_mfma_f32_16x16x32_bf16(af0, vf0, accp[dt], 0, 0, 0);
        accp[dt] = __builtin_amdgcn_mfma_f32_16x16x32_bf16(af1, vf1, accp[dt], 0, 0, 0);
        accp[dt] = __builtin_amdgcn_mfma_f32_16x16x32_bf16(af2, vf2, accp[dt], 0, 0, 0);
    }

#pragma unroll
    for (int dt = 0; dt < 4; ++dt) {
        const int d = dt * 16 + q15;
#pragma unroll
        for (int r = 0; r < 4; ++r) {
            const int s = s0 + w * 16 + p * 4 + r;
            ctx[(((size_t)(b * SEQ + s)) << 10) + h * 64 + d] = f2bf(accp[dt][r]);
        }
    }
}

// ---------------- launch ----------------
extern "C" void kernel_launch(void* const* d_in, const int* in_sizes, int n_in,
                              void* d_out, int out_size, void* d_ws, size_t ws_size,
                              hipStream_t stream)
{
    const float* x     = (const float*)d_in[0];
    const float* w_qkv = (const float*)d_in[1];
    const float* b_qkv = (const float*)d_in[2];
    const float* w_out = (const float*)d_in[3];
    const float* b_out = (const float*)d_in[4];
    float* out = (float*)d_out;

    char* ws = (char*)d_ws;
    short* x_bf    = (short*)(ws);                       // 8 MB
    short* wqkv_bf = (short*)(ws + (8ull  << 20));       // 6 MB
    short* wout_bf = (short*)(ws + (14ull << 20));       // 2 MB
    short* qkvb    = (short*)(ws + (16ull << 20));       // 24 MB: q,k [bh][s][d]; v^T [bh][d][s]
    short* ctx     = (short*)(ws + (48ull << 20));       // 8 MB

    cvt3_k<<<dim3(4096), 256, 0, stream>>>(x, x_bf, w_qkv, wqkv_bf, w_out, wout_bf);

    gemm1_k<<<dim3(512), 256, 0, stream>>>(x_bf, wqkv_bf, b_qkv, qkvb);

    swattn4_k<<<dim3((SEQ / 64) * BATCH * NHEADS), 256, 0, stream>>>(qkvb, (short*)ctx);

    gemm2_k<<<dim3(512), 256, 0, stream>>>(ctx, wout_bf, b_out, out);
}